// Round 3
// baseline (3514.629 us; speedup 1.0000x reference)
//
#include <hip/hip_runtime.h>
#include <hip/hip_bf16.h>

// LGA3D2: out = A_g(A_g(x)); A_g is a 5x5 spatial x 3-depth guided aggregation.
// out[b,c,d,h,w] = sum_{i,j in 5x5, k in 0..2} g[b,(i*5+j)*3+k,h,w] * x[b,c,d+k-1,h+i-2,w+j-2]
// x: [B,C,D,H,W] fp32, g: [B,75,H,W] fp32.

constexpr int RAD = 2;
constexpr int BB = 2, CC = 16, DD = 48, HH = 128, WW = 256;
constexpr int GG = 75;
constexpr int PLANE = HH * WW;

constexpr int WPT = 4;            // outputs per thread along W
constexpr int NWT = WW / WPT;     // 64 w-threads (one wave spans W)
constexpr int DPG = 8;            // depths per thread (8 keeps VGPR < 128)
constexpr int NDG = DD / DPG;     // 6 depth groups -> 384 threads/block
constexpr int TPB = NWT * NDG;    // 384

__device__ __forceinline__ float bf2f(unsigned short u) {
  union { unsigned int i; float f; } c; c.i = ((unsigned int)u) << 16; return c.f;
}
__device__ __forceinline__ unsigned short f2bf(float f) {
  union { float f; unsigned int i; } c; c.f = f;
  unsigned int r = c.i + 0x7FFFu + ((c.i >> 16) & 1u);  // round-nearest-even
  return (unsigned short)(r >> 16);
}

__device__ __forceinline__ void load4(float* v, const float* p, int off) {
  const float4 t = *reinterpret_cast<const float4*>(p + off);
  v[0] = t.x; v[1] = t.y; v[2] = t.z; v[3] = t.w;
}
__device__ __forceinline__ void load4(float* v, const __hip_bfloat16* p, int off) {
  const ushort4 t = *reinterpret_cast<const ushort4*>(p + off);
  v[0] = bf2f(t.x); v[1] = bf2f(t.y); v[2] = bf2f(t.z); v[3] = bf2f(t.w);
}
__device__ __forceinline__ void store4(float* p, int off, const float* v) {
  float4 t; t.x = v[0]; t.y = v[1]; t.z = v[2]; t.w = v[3];
  *reinterpret_cast<float4*>(p + off) = t;
}
__device__ __forceinline__ void store4(__hip_bfloat16* p, int off, const float* v) {
  ushort4 t; t.x = f2bf(v[0]); t.y = f2bf(v[1]); t.z = f2bf(v[2]); t.w = f2bf(v[3]);
  *reinterpret_cast<ushort4*>(p + off) = t;
}

// One pass. Block = (b, c, h); 384 threads = 64 w-threads x 6 depth-groups.
// Each thread: WPT=4 w-outputs x DPG=8 depth-outputs in registers. Scatter
// over depth: x row at depth d feeds k=0,1,2 into out depths d+1,d,d-1.
template <typename IT, typename OT>
__global__ __launch_bounds__(TPB, 4) void lga_pass(const IT* __restrict__ x,
                                                   const float* __restrict__ g,
                                                   OT* __restrict__ out) {
  // XCD-bijective swizzle: nwg=4096 (div by 8). Consecutive logical ids
  // (h fastest) stay on one XCD -> 5-row h-halo served by that XCD's L2.
  constexpr int NWG = BB * CC * HH;       // 4096
  const int bx = blockIdx.x;
  const int lid = (bx & 7) * (NWG >> 3) + (bx >> 3);
  const int h = lid % HH;
  const int c = (lid / HH) % CC;
  const int b = lid / (HH * CC);

  const int wt = threadIdx.x & 63;        // w-thread within wave
  const int dg = threadIdx.x >> 6;        // depth group (wave-uniform)
  const int w0 = wt * WPT;
  const int d0 = dg * DPG;
  const bool wok_lo = (wt > 0);
  const bool wok_hi = (wt < NWT - 1);

  float acc[DPG][WPT];
#pragma unroll
  for (int a = 0; a < DPG; ++a)
#pragma unroll
    for (int q = 0; q < WPT; ++q) acc[a][q] = 0.f;

  // 32-bit offsets throughout (max index < 2^31): single-vgpr address math.
  const IT* xb = x + (size_t)(b * CC + c) * DD * PLANE;
  const float* gb = g + (size_t)b * GG * PLANE;
  const int gbase = h * WW + w0;

  for (int i = 0; i < 5; ++i) {
    const int hr = h + i - RAD;
    if (hr < 0 || hr >= HH) continue;     // block-uniform (zero pad)

    // Guidance for this i-row: channels i*15..i*15+14 at (h,w0), kept in
    // registers and reused across all DPG+2 depth rows below.
    float gr[15][4];
#pragma unroll
    for (int t = 0; t < 15; ++t) load4(gr[t], gb, (i * 15 + t) * PLANE + gbase);

    const int rowbase = hr * WW + w0;

#pragma unroll
    for (int a = -1; a <= DPG; ++a) {     // x depth rows d0-1 .. d0+DPG
      bool dok = true;
      if (a == -1)  dok = (d0 > 0);               // depth zero-pad low
      if (a == DPG) dok = (d0 + DPG < DD);        // depth zero-pad high

      // 12-float register window covering w = w0-4 .. w0+7
      float v[12];
      if (dok) {
        const int roff = (d0 + a) * PLANE + rowbase;
        if (wok_lo) load4(v + 0, xb, roff - 4);
        else { v[0] = v[1] = v[2] = v[3] = 0.f; }
        load4(v + 4, xb, roff);
        if (wok_hi) load4(v + 8, xb, roff + 4);
        else { v[8] = v[9] = v[10] = v[11] = 0.f; }
      } else {
#pragma unroll
        for (int t = 0; t < 12; ++t) v[t] = 0.f;
      }

#pragma unroll
      for (int j = 0; j < 5; ++j)
#pragma unroll
        for (int k = 0; k < 3; ++k) {
          const int ai = a + 1 - k;       // output depth index (compile-time)
          if (ai < 0 || ai >= DPG) continue;
#pragma unroll
          for (int q = 0; q < WPT; ++q)
            acc[ai][q] = fmaf(gr[j * 3 + k][q], v[q + j + 2], acc[ai][q]);
        }
    }
  }

  OT* ob = out + (size_t)(b * CC + c) * DD * PLANE;
  const int obase = d0 * PLANE + h * WW + w0;
#pragma unroll
  for (int ai = 0; ai < DPG; ++ai) store4(ob, obase + ai * PLANE, acc[ai]);
}

extern "C" void kernel_launch(void* const* d_in, const int* in_sizes, int n_in,
                              void* d_out, int out_size, void* d_ws, size_t ws_size,
                              hipStream_t stream) {
  const float* x = (const float*)d_in[0];
  const float* g = (const float*)d_in[1];
  float* out = (float*)d_out;

  const size_t elems = (size_t)BB * CC * DD * HH * WW;
  const dim3 grid(BB * CC * HH);
  const dim3 block(TPB);

  if (ws_size >= elems * sizeof(float)) {
    float* y = (float*)d_ws;
    lga_pass<float, float><<<grid, block, 0, stream>>>(x, g, y);
    lga_pass<float, float><<<grid, block, 0, stream>>>(y, g, out);
  } else {
    __hip_bfloat16* y = (__hip_bfloat16*)d_ws;
    lga_pass<float, __hip_bfloat16><<<grid, block, 0, stream>>>(x, g, y);
    lga_pass<__hip_bfloat16, float><<<grid, block, 0, stream>>>(y, g, out);
  }
}

// Round 4
// 1307.061 us; speedup vs baseline: 2.6890x; 2.6890x over previous
//
#include <hip/hip_runtime.h>
#include <hip/hip_bf16.h>

// LGA3D2: out = A_g(A_g(x)); A_g is a 5x5 spatial x 3-depth guided aggregation.
// out[b,c,d,h,w] = sum_{i,j in 5x5, k in 0..2} g[b,(i*5+j)*3+k,h,w] * x[b,c,d+k-1,h+i-2,w+j-2]
// x: [B,C,D,H,W] fp32, g: [B,75,H,W] fp32.

constexpr int RAD = 2;
constexpr int BB = 2, CC = 16, DD = 48, HH = 128, WW = 256;
constexpr int GG = 75;
constexpr int PLANE = HH * WW;

constexpr int WPT = 4;            // outputs per thread along W
constexpr int NWT = WW / WPT;     // 64 w-threads = one wave spans W
constexpr int DPG = 4;            // depths per thread (k-split keeps VGPR ~56)
constexpr int NDGB = 4;           // depth groups per block -> 256 threads
constexpr int DCHUNK = DPG * NDGB;        // 16 depths per block
constexpr int NCH = DD / DCHUNK;          // 3 depth chunks

__device__ __forceinline__ float bf2f(unsigned short u) {
  union { unsigned int i; float f; } c; c.i = ((unsigned int)u) << 16; return c.f;
}
__device__ __forceinline__ unsigned short f2bf(float f) {
  union { float f; unsigned int i; } c; c.f = f;
  unsigned int r = c.i + 0x7FFFu + ((c.i >> 16) & 1u);  // round-nearest-even
  return (unsigned short)(r >> 16);
}

__device__ __forceinline__ void load4(float* v, const float* p, int off) {
  const float4 t = *reinterpret_cast<const float4*>(p + off);
  v[0] = t.x; v[1] = t.y; v[2] = t.z; v[3] = t.w;
}
__device__ __forceinline__ void load4(float* v, const __hip_bfloat16* p, int off) {
  const ushort4 t = *reinterpret_cast<const ushort4*>(p + off);
  v[0] = bf2f(t.x); v[1] = bf2f(t.y); v[2] = bf2f(t.z); v[3] = bf2f(t.w);
}
__device__ __forceinline__ void load2(float* v, const float* p, int off) {
  const float2 t = *reinterpret_cast<const float2*>(p + off);
  v[0] = t.x; v[1] = t.y;
}
__device__ __forceinline__ void load2(float* v, const __hip_bfloat16* p, int off) {
  const ushort2 t = *reinterpret_cast<const ushort2*>(p + off);
  v[0] = bf2f(t.x); v[1] = bf2f(t.y);
}
__device__ __forceinline__ void store4(float* p, int off, const float* v) {
  float4 t; t.x = v[0]; t.y = v[1]; t.z = v[2]; t.w = v[3];
  *reinterpret_cast<float4*>(p + off) = t;
}
__device__ __forceinline__ void store4(__hip_bfloat16* p, int off, const float* v) {
  ushort4 t; t.x = f2bf(v[0]); t.y = f2bf(v[1]); t.z = f2bf(v[2]); t.w = f2bf(v[3]);
  *reinterpret_cast<ushort4*>(p + off) = t;
}

// One pass. Block = (b, c, dchunk, h); 256 threads = 64 w-threads x 4 depth
// groups. k-split gather form: for fixed (i,k) only 5 guidance channels are
// live (20 VGPR) and each x row feeds exactly one output depth. Per-thread
// live state ~44 floats -> VGPR < 64 -> 8 waves/SIMD for latency hiding.
template <typename IT, typename OT>
__global__ __launch_bounds__(256) void lga_pass(const IT* __restrict__ x,
                                                const float* __restrict__ g,
                                                OT* __restrict__ out) {
  // XCD-bijective swizzle; h fastest within an XCD chunk so the 5-row
  // h-halo of x is served by that XCD's L2.
  constexpr int NWG = BB * CC * NCH * HH;   // 12288, divisible by 8
  const int bx = blockIdx.x;
  const int lid = (bx & 7) * (NWG >> 3) + (bx >> 3);
  const int h = lid % HH;
  const int r1 = lid / HH;
  const int dch = r1 % NCH;
  const int c = (r1 / NCH) % CC;
  const int b = r1 / (NCH * CC);

  const int wt = threadIdx.x & 63;          // w-thread within wave
  const int dg = threadIdx.x >> 6;          // depth group (wave-uniform)
  const int w0 = wt * WPT;
  const int d0 = dch * DCHUNK + dg * DPG;   // wave-uniform

  float acc[DPG][WPT];
#pragma unroll
  for (int a = 0; a < DPG; ++a)
#pragma unroll
    for (int q = 0; q < WPT; ++q) acc[a][q] = 0.f;

  const IT* xb = x + (size_t)(b * CC + c) * DD * PLANE;  // block-uniform base
  const float* gb = g + (size_t)b * GG * PLANE;
  const int gbase = h * WW + w0;
  const bool wlo = (wt > 0);
  const bool whi = (wt < NWT - 1);

  for (int i = 0; i < 5; ++i) {
    const int hr = h + i - RAD;
    if (hr < 0 || hr >= HH) continue;       // block-uniform (zero pad)
    const int rowb = hr * WW + w0;

#pragma unroll
    for (int k = 0; k < 3; ++k) {
      // 5 guidance channels for this (i,k): j = 0..4
      float gk[5][WPT];
#pragma unroll
      for (int j = 0; j < 5; ++j)
        load4(gk[j], gb, ((i * 5 + j) * 3 + k) * PLANE + gbase);

#pragma unroll
      for (int ai = 0; ai < DPG; ++ai) {
        const int dx = d0 + ai + (k - 1);   // x depth row feeding out[d0+ai]
        // Depth zero-pad: only (k=0,ai=0) can underflow, (k=2,ai=3) overflow.
        bool dok = true;
        if (k == 0 && ai == 0)       dok = (d0 > 0);
        if (k == 2 && ai == DPG - 1) dok = (d0 + DPG < DD);
        if (!dok) continue;                 // wave-uniform branch

        // 8-float window: w0-2 .. w0+5 (float2 + float4 + float2, aligned)
        float v[8];
        const int ro = dx * PLANE + rowb;
        if (wlo) load2(v + 0, xb, ro - 2);
        else { v[0] = 0.f; v[1] = 0.f; }
        load4(v + 2, xb, ro);
        if (whi) load2(v + 6, xb, ro + 4);
        else { v[6] = 0.f; v[7] = 0.f; }

#pragma unroll
        for (int j = 0; j < 5; ++j)
#pragma unroll
          for (int q = 0; q < WPT; ++q)
            acc[ai][q] = fmaf(gk[j][q], v[q + j], acc[ai][q]);
      }
    }
  }

  OT* ob = out + (size_t)(b * CC + c) * DD * PLANE;
  const int obase = d0 * PLANE + h * WW + w0;
#pragma unroll
  for (int ai = 0; ai < DPG; ++ai) store4(ob, obase + ai * PLANE, acc[ai]);
}

extern "C" void kernel_launch(void* const* d_in, const int* in_sizes, int n_in,
                              void* d_out, int out_size, void* d_ws, size_t ws_size,
                              hipStream_t stream) {
  const float* x = (const float*)d_in[0];
  const float* g = (const float*)d_in[1];
  float* out = (float*)d_out;

  const size_t elems = (size_t)BB * CC * DD * HH * WW;
  const dim3 grid(BB * CC * NCH * HH);   // 12288
  const dim3 block(NWT * NDGB);          // 256

  if (ws_size >= elems * sizeof(float)) {
    float* y = (float*)d_ws;
    lga_pass<float, float><<<grid, block, 0, stream>>>(x, g, y);
    lga_pass<float, float><<<grid, block, 0, stream>>>(y, g, out);
  } else {
    __hip_bfloat16* y = (__hip_bfloat16*)d_ws;
    lga_pass<float, __hip_bfloat16><<<grid, block, 0, stream>>>(x, g, y);
    lga_pass<__hip_bfloat16, float><<<grid, block, 0, stream>>>(y, g, out);
  }
}

// Round 5
// 509.163 us; speedup vs baseline: 6.9028x; 2.5671x over previous
//
#include <hip/hip_runtime.h>
#include <hip/hip_bf16.h>

// LGA3D2: out = A_g(A_g(x)); A_g is a 5x5 spatial x 3-depth guided aggregation.
// out[b,c,d,h,w] = sum_{i,j in 5x5, k in 0..2} g[b,(i*5+j)*3+k,h,w] * x[b,c,d+k-1,h+i-2,w+j-2]
// x: [B,C,D,H,W] fp32, g: [B,75,H,W] fp32.
//
// Structure: block = (b,c,dchunk=16,h); 4 waves x 64 lanes. Per i-tap the
// 18-depth x-slab (1 h-row, full W + zero pads) is staged into LDS with
// async global_load_lds, double-buffered across i (stage i+1 || compute i).
// Compute is scatter-form from LDS: each slab row read once (4x ds_read_b64),
// feeds 60 FMAs into 3 depth accumulators. Zeroed slab borders remove all
// boundary branches from the hot loop.

constexpr int RAD = 2;
constexpr int BB = 2, CC = 16, DD = 48, HH = 128, WW = 256;
constexpr int GG = 75;
constexpr int PLANE = HH * WW;

constexpr int WPT = 4;            // outputs per lane along W
constexpr int DPG = 4;            // depths per lane
constexpr int NDGB = 4;           // waves per block
constexpr int DCHUNK = 16;        // depths per block
constexpr int NCH = DD / DCHUNK;  // 3
constexpr int SROWS = DCHUNK + 2; // 18 slab depth-rows

using uint = unsigned int;

__device__ __forceinline__ float lo16(uint u) { union {uint i; float f;} c; c.i = u << 16; return c.f; }
__device__ __forceinline__ float hi16(uint u) { union {uint i; float f;} c; c.i = u & 0xFFFF0000u; return c.f; }
__device__ __forceinline__ unsigned short f2bf(float f) {
  union { float f; uint i; } c; c.f = f;
  uint r = c.i + 0x7FFFu + ((c.i >> 16) & 1u);
  return (unsigned short)(r >> 16);
}
__device__ __forceinline__ void store4(float* p, int off, const float* v) {
  float4 t; t.x = v[0]; t.y = v[1]; t.z = v[2]; t.w = v[3];
  *reinterpret_cast<float4*>(p + off) = t;
}
__device__ __forceinline__ void store4(__hip_bfloat16* p, int off, const float* v) {
  ushort4 t; t.x = f2bf(v[0]); t.y = f2bf(v[1]); t.z = f2bf(v[2]); t.w = f2bf(v[3]);
  *reinterpret_cast<ushort4*>(p + off) = t;
}
__device__ __forceinline__ void gload_lds16(const void* gp, void* lp) {
  __builtin_amdgcn_global_load_lds(
      (const __attribute__((address_space(1))) void*)gp,
      (__attribute__((address_space(3))) void*)lp, 16, 0, 0);
}

template <typename IT, typename OT>
__global__ __launch_bounds__(256) void lga_pass(const IT* __restrict__ x,
                                                const float* __restrict__ g,
                                                OT* __restrict__ out) {
  constexpr bool F32 = (sizeof(IT) == 4);
  // Row layout: [16B zero pad][core: 256 elems][16B zero pad]
  constexpr int ROWB = F32 ? (16 + 1024 + 16) : (16 + 512 + 16);
  constexpr int SLABB = SROWS * ROWB;
  __shared__ unsigned char lds[2][SLABB];

  // XCD-bijective swizzle, h fastest -> h-halo L2 reuse within an XCD.
  constexpr int NWG = BB * CC * NCH * HH;   // 12288
  const int bx = blockIdx.x;
  const int lid = (bx & 7) * (NWG >> 3) + (bx >> 3);
  const int h = lid % HH;
  const int r1 = lid / HH;
  const int dch = r1 % NCH;
  const int c = (r1 / NCH) % CC;
  const int b = r1 / (NCH * CC);

  const int tid = threadIdx.x;
  const int lane = tid & 63;
  const int dg = tid >> 6;          // wave index (wave-uniform)
  const int w0 = lane * WPT;
  const int d0 = dch * DCHUNK + dg * DPG;

  const IT* xb = x + (size_t)(b * CC + c) * DD * PLANE;
  const float* gb = g + (size_t)b * GG * PLANE;
  const int gbase = h * WW + w0;

  // ---- init: zero w-pads (all rows, both bufs) + out-of-range depth rows
  {
    const uint4 z = make_uint4(0, 0, 0, 0);
    if (tid < 2 * SROWS) {
      const int buf = tid / SROWS, s = tid % SROWS;
      *(uint4*)&lds[buf][s * ROWB] = z;
      *(uint4*)&lds[buf][s * ROWB + ROWB - 16] = z;
    }
    constexpr int C16 = (ROWB - 32) / 16;   // core 16B chunks per row
    if (dch == 0 && tid < 2 * C16) {
      const int buf = tid / C16, l = tid % C16;
      *(uint4*)&lds[buf][16 + l * 16] = z;                      // depth -1
    }
    if (dch == NCH - 1 && tid < 2 * C16) {
      const int buf = tid / C16, l = tid % C16;
      *(uint4*)&lds[buf][(SROWS - 1) * ROWB + 16 + l * 16] = z; // depth 48
    }
  }

  float acc[DPG][WPT];
#pragma unroll
  for (int a = 0; a < DPG; ++a)
#pragma unroll
    for (int q = 0; q < WPT; ++q) acc[a][q] = 0.f;

  const int ilo = (h >= RAD) ? 0 : RAD - h;
  const int him = HH - 1 + RAD - h;
  const int ihi = (him < 4) ? him : 4;

  // Async-stage one i-slab: wave dg stages rows s = dg, dg+4, ...
  auto stage = [&](int buf, int i) {
    const int hr = h + i - RAD;
#pragma unroll
    for (int t = 0; t < 5; ++t) {
      const int s = dg + NDGB * t;
      if (s >= SROWS) break;                       // wave-uniform
      if (s == 0 && dch == 0) continue;            // pre-zeroed
      if (s == SROWS - 1 && dch == NCH - 1) continue;
      const int dd = dch * DCHUNK + s - 1;
      void* lp = &lds[buf][s * ROWB + 16];         // wave-uniform base
      if constexpr (F32) {
        gload_lds16(xb + (size_t)dd * PLANE + hr * WW + lane * 4, lp);
      } else {
        if (lane < 32)                             // 32 lanes x 16B = 512B row
          gload_lds16(xb + (size_t)dd * PLANE + hr * WW + lane * 8, lp);
      }
    }
  };

  int cur = 0;
  stage(0, ilo);
  __syncthreads();   // drains stage(ilo) + init ds_writes

  for (int ii = ilo; ii <= ihi; ++ii) {
    // guidance for this i: 15 channels, float4 at (h, w0) — L2-resident
    float gr[15][WPT];
#pragma unroll
    for (int t = 0; t < 15; ++t) {
      const float4 t4 = *(const float4*)(gb + (size_t)(ii * 15 + t) * PLANE + gbase);
      gr[t][0] = t4.x; gr[t][1] = t4.y; gr[t][2] = t4.z; gr[t][3] = t4.w;
    }

    if (ii < ihi) stage(cur ^ 1, ii + 1);   // async, lands under compute

    const unsigned char* sb = lds[cur];
#pragma unroll
    for (int a = -1; a <= DPG; ++a) {       // x depth rows d0-1 .. d0+4
      const int s = dg * DPG + a + 1;       // slab row (wave-uniform)
      float v[8];                           // x at w = w0-2 .. w0+5
      if constexpr (F32) {
        const unsigned char* rp = sb + s * ROWB + 16 * lane + 8;
        const float2 t0 = *(const float2*)(rp);
        const float2 t1 = *(const float2*)(rp + 8);
        const float2 t2 = *(const float2*)(rp + 16);
        const float2 t3 = *(const float2*)(rp + 24);
        v[0] = t0.x; v[1] = t0.y; v[2] = t1.x; v[3] = t1.y;
        v[4] = t2.x; v[5] = t2.y; v[6] = t3.x; v[7] = t3.y;
      } else {
        const unsigned char* rp = sb + s * ROWB + 8 * lane + 12;
        const uint c0 = *(const uint*)(rp);
        const uint c1 = *(const uint*)(rp + 4);
        const uint c2 = *(const uint*)(rp + 8);
        const uint c3 = *(const uint*)(rp + 12);
        v[0] = lo16(c0); v[1] = hi16(c0); v[2] = lo16(c1); v[3] = hi16(c1);
        v[4] = lo16(c2); v[5] = hi16(c2); v[6] = lo16(c3); v[7] = hi16(c3);
      }
      // scatter: row d0+a feeds acc[a+1-k] with weight channel j*3+k
#pragma unroll
      for (int k = 0; k < 3; ++k) {
        const int ai = a + 1 - k;
        if (ai < 0 || ai >= DPG) continue;  // compile-time
#pragma unroll
        for (int j = 0; j < 5; ++j)
#pragma unroll
          for (int q = 0; q < WPT; ++q)
            acc[ai][q] = fmaf(gr[j * 3 + k][q], v[q + j], acc[ai][q]);
      }
    }
    __syncthreads();   // stage(i+1) drained; buf[cur] reads done before reuse
    cur ^= 1;
  }

  OT* ob = out + (size_t)(b * CC + c) * DD * PLANE;
  const int obase = d0 * PLANE + h * WW + w0;
#pragma unroll
  for (int ai = 0; ai < DPG; ++ai) store4(ob, obase + ai * PLANE, acc[ai]);
}

extern "C" void kernel_launch(void* const* d_in, const int* in_sizes, int n_in,
                              void* d_out, int out_size, void* d_ws, size_t ws_size,
                              hipStream_t stream) {
  const float* x = (const float*)d_in[0];
  const float* g = (const float*)d_in[1];
  float* out = (float*)d_out;

  const size_t elems = (size_t)BB * CC * DD * HH * WW;
  const dim3 grid(BB * CC * NCH * HH);   // 12288
  const dim3 block(64 * NDGB);           // 256

  if (ws_size >= elems * sizeof(float)) {
    float* y = (float*)d_ws;
    lga_pass<float, float><<<grid, block, 0, stream>>>(x, g, y);
    lga_pass<float, float><<<grid, block, 0, stream>>>(y, g, out);
  } else {
    __hip_bfloat16* y = (__hip_bfloat16*)d_ws;
    lga_pass<float, __hip_bfloat16><<<grid, block, 0, stream>>>(x, g, y);
    lga_pass<__hip_bfloat16, float><<<grid, block, 0, stream>>>(y, g, out);
  }
}